// Round 8
// baseline (221.573 us; speedup 1.0000x reference)
//
#include <hip/hip_runtime.h>

typedef unsigned short u16;
typedef unsigned int u32;
typedef __attribute__((ext_vector_type(8))) short short8;
typedef __attribute__((ext_vector_type(4))) float f32x4;
typedef __attribute__((ext_vector_type(16))) float f32x16;

#define DEV static __device__ __forceinline__

DEV u16 f2bf(float x) {
  union { float f; u32 u; } v; v.f = x;
  u32 r = v.u + 0x7fffu + ((v.u >> 16) & 1u);
  return (u16)(r >> 16);
}
DEV float bf2f(u16 x) {
  union { u32 u; float f; } v; v.u = ((u32)x) << 16;
  return v.f;
}
DEV u32 cvtpk(float lo, float hi) {  // D.lo=bf16(lo), D.hi=bf16(hi), RNE
  u32 r;
  asm("v_cvt_pk_bf16_f32 %0, %1, %2" : "=v"(r) : "v"(lo), "v"(hi));
  return r;
}
DEV void swap32(u32& a, u32& b) {  // a' = [a.lo32 | b.lo32], b' = [a.hi32 | b.hi32]
  asm("v_permlane32_swap_b32 %0, %1" : "+v"(a), "+v"(b));
}

DEV void gload_lds16(const void* g, void* l) {
  __builtin_amdgcn_global_load_lds(
      (__attribute__((address_space(1))) u32*)((void*)g),
      (__attribute__((address_space(3))) u32*)l, 16, 0, 0);
}

DEV void mfma_bf16(f32x4& d, short8 a, short8 b) {
  asm("v_mfma_f32_16x16x32_bf16 %0, %1, %2, %0" : "+v"(d) : "v"(a), "v"(b));
}
DEV void mfma32(f32x16& d, short8 a, short8 b) {
  asm("v_mfma_f32_32x32x16_bf16 %0, %1, %2, %0" : "+v"(d) : "v"(a), "v"(b));
}

// ---------------- fused prep: x->bf16 (blocks 0..6143), W->Wt bf16 (6144..7167),
// ---------------- rope sincos table (7168..7423) ----------------
__global__ __launch_bounds__(256) void k_prep(const float* __restrict__ x0, const float* __restrict__ x1,
                                              const float* __restrict__ x2, u16* __restrict__ o0,
                                              u16* __restrict__ o1, u16* __restrict__ o2,
                                              const float* __restrict__ W0, const float* __restrict__ W1,
                                              const float* __restrict__ W2, const float* __restrict__ W3,
                                              u16* __restrict__ T0, u16* __restrict__ T1,
                                              u16* __restrict__ T2, u16* __restrict__ T3,
                                              float2* __restrict__ tab) {
  int bid = blockIdx.x;
  int t = threadIdx.x;
  if (bid < 6144) {  // fp32 -> bf16 cast, 8 elems/thread
    int z = bid >> 11;
    const float* in = (z == 0) ? x0 : (z == 1) ? x1 : x2;
    u16* out = (z == 0) ? o0 : (z == 1) ? o1 : o2;
    int i = (bid & 2047) * 256 + t;
    const float4* p = (const float4*)in;
    float4 a = p[i * 2], b = p[i * 2 + 1];
    uint4 o;
    o.x = cvtpk(a.x, a.y); o.y = cvtpk(a.z, a.w);
    o.z = cvtpk(b.x, b.y); o.w = cvtpk(b.z, b.w);
    ((uint4*)out)[i] = o;
  } else if (bid < 7168) {  // W[k][n] -> Wt[n][k] bf16, 64x64 tile
    int q = bid - 6144;
    int z = q >> 8;
    const float* W = (z == 0) ? W0 : (z == 1) ? W1 : (z == 2) ? W2 : W3;
    u16* Wt = (z == 0) ? T0 : (z == 1) ? T1 : (z == 2) ? T2 : T3;
    __shared__ u16 tile[64][65];
    int k0 = ((q >> 4) & 15) * 64, n0 = (q & 15) * 64;
    int rr = t >> 4, cc = (t & 15) * 4;
#pragma unroll
    for (int i = 0; i < 4; ++i) {
      int r = rr + i * 16;
      float4 v = *(const float4*)&W[(size_t)(k0 + r) * 1024 + n0 + cc];
      tile[r][cc + 0] = f2bf(v.x); tile[r][cc + 1] = f2bf(v.y);
      tile[r][cc + 2] = f2bf(v.z); tile[r][cc + 3] = f2bf(v.w);
    }
    __syncthreads();
#pragma unroll
    for (int i = 0; i < 4; ++i) {
      int n = rr + i * 16;
      u16 a0 = tile[cc + 0][n], a1 = tile[cc + 1][n], a2 = tile[cc + 2][n], a3 = tile[cc + 3][n];
      uint2 pk;
      pk.x = (u32)a0 | ((u32)a1 << 16);
      pk.y = (u32)a2 | ((u32)a3 << 16);
      *(uint2*)&Wt[(size_t)(n0 + n) * 1024 + k0 + cc] = pk;
    }
  } else {  // rope table: tab[s*32+dp] = (cos, sin) of s * 10000^(-dp/32)
    int idx = (bid - 7168) * 256 + t;
    int s = idx >> 5, dp = idx & 31;
    float theta = exp2f((float)dp * (-2.0f / 64.0f) * 13.287712379549449f);
    float ang = (float)s * theta;
    float sn, cs;
    sincosf(ang, &sn, &cs);
    tab[idx] = make_float2(cs, sn);
  }
}

// ---------------- V (b,h,s,d) bf16 -> Vt (b,h,d,s) bf16, 64x64 tiles ----------------
__global__ __launch_bounds__(256) void k_vtrans(const u16* __restrict__ in, u16* __restrict__ out) {
  __shared__ u16 tile[64][65];
  int t = threadIdx.x;
  int s0 = blockIdx.x * 64;
  size_t base = (size_t)blockIdx.y * 131072;
#pragma unroll
  for (int p = 0; p < 2; ++p) {
    int i = p * 256 + t;
    int r = i >> 3, c = i & 7;
    short8 v = *(const short8*)(in + base + (size_t)(s0 + r) * 64 + c * 8);
#pragma unroll
    for (int j = 0; j < 8; ++j) tile[r][c * 8 + j] = (u16)(unsigned short)v[j];
  }
  __syncthreads();
#pragma unroll
  for (int p = 0; p < 2; ++p) {
    int i = p * 256 + t;
    int d = i >> 3, c = i & 7;
    short8 o;
#pragma unroll
    for (int j = 0; j < 8; ++j) o[j] = (short)tile[c * 8 + j][d];
    *(short8*)(out + base + (size_t)d * 2048 + s0 + c * 8) = o;
  }
}

// ---------------- GEMM core, BK=64, XOR-swizzled LDS (2-way conflict = free) ----------------
#define GEMM_BODY(A_, Bt_)                                                                       \
  __shared__ __align__(16) char sA[16384];                                                       \
  __shared__ __align__(16) char sB[16384];                                                       \
  int tid = threadIdx.x, lane = tid & 63, w = tid >> 6;                                          \
  int l15 = lane & 15, lg = lane >> 4;                                                           \
  int bm = blockIdx.x * 128, bn = blockIdx.y * 128;                                              \
  int wm = (w >> 1) * 64, wn = (w & 1) * 64;                                                     \
  f32x4 acc[4][4];                                                                               \
  _Pragma("unroll") for (int i = 0; i < 4; ++i)                                                  \
      _Pragma("unroll") for (int j = 0; j < 4; ++j) acc[i][j] = (f32x4){0.f, 0.f, 0.f, 0.f};     \
  for (int kt = 0; kt < 16; ++kt) {                                                              \
    _Pragma("unroll") for (int p = 0; p < 4; ++p) {                                              \
      int idx = p * 256 + tid;                                                                   \
      int row = idx >> 3;                                                                        \
      int c8 = (idx & 7) ^ (row & 7);                                                            \
      gload_lds16(A_ + (size_t)(bm + row) * 1024 + kt * 64 + c8 * 8, sA + p * 4096 + w * 1024);  \
      gload_lds16(Bt_ + (size_t)(bn + row) * 1024 + kt * 64 + c8 * 8, sB + p * 4096 + w * 1024); \
    }                                                                                            \
    __syncthreads();                                                                             \
    short8 af[4][2], bf[4][2];                                                                   \
    _Pragma("unroll") for (int i = 0; i < 4; ++i) _Pragma("unroll") for (int s = 0; s < 2; ++s) { \
      int cs = ((s * 4 + lg) ^ (l15 & 7)) * 16;                                                  \
      af[i][s] = *(const short8*)(sA + (wm + i * 16 + l15) * 128 + cs);                          \
      bf[i][s] = *(const short8*)(sB + (wn + i * 16 + l15) * 128 + cs);                          \
    }                                                                                            \
    _Pragma("unroll") for (int s = 0; s < 2; ++s)                                                \
        _Pragma("unroll") for (int i = 0; i < 4; ++i)                                            \
            _Pragma("unroll") for (int j = 0; j < 4; ++j) mfma_bf16(acc[i][j], af[i][s], bf[j][s]); \
    __syncthreads();                                                                             \
  }

// MODE 1: write fp32 row-major (output projection).
template <int MODE>
__global__ __launch_bounds__(256) void k_gemm(const u16* __restrict__ A, const u16* __restrict__ Bt,
                                              const float* __restrict__ bias, void* __restrict__ dst) {
  GEMM_BODY(A, Bt)
  float bv[4];
#pragma unroll
  for (int j = 0; j < 4; ++j) bv[j] = bias[bn + wn + j * 16 + l15];
#pragma unroll
  for (int i = 0; i < 4; ++i) {
#pragma unroll
    for (int j = 0; j < 4; ++j) {
#pragma unroll
      for (int r = 0; r < 4; ++r) {
        int m = bm + wm + i * 16 + lg * 4 + r;
        int n = bn + wn + j * 16 + l15;
        float v = acc[i][j][r] + bv[j];
        if (MODE == 0) {
          int bb = m >> 11, s = m & 2047, h = n >> 6, d = n & 63;
          ((u16*)dst)[(((size_t)(bb * 16 + h)) * 2048 + s) * 64 + d] = f2bf(v);
        } else {
          ((float*)dst)[(size_t)m * 1024 + n] = v;
        }
      }
    }
  }
}

// QKV fused over blockIdx.z; RoPE fused into epilogue for z<2 (Q,K).
__global__ __launch_bounds__(256) void k_gemm_qkv(const u16* __restrict__ Aq, const u16* __restrict__ Ak,
                                                  const u16* __restrict__ Av, const u16* __restrict__ Wq,
                                                  const u16* __restrict__ Wk, const u16* __restrict__ Wv,
                                                  const float* __restrict__ bq, const float* __restrict__ bk,
                                                  const float* __restrict__ bv,
                                                  const float2* __restrict__ tab, u16* __restrict__ Qo,
                                                  u16* __restrict__ Ko, u16* __restrict__ Vo) {
  int z = blockIdx.z;
  const u16* A = (z == 0) ? Aq : (z == 1) ? Ak : Av;
  const u16* Bt = (z == 0) ? Wq : (z == 1) ? Wk : Wv;
  const float* bias = (z == 0) ? bq : (z == 1) ? bk : bv;
  u16* dst = (z == 0) ? Qo : (z == 1) ? Ko : Vo;
  GEMM_BODY(A, Bt)
  float bvv[4];
#pragma unroll
  for (int j = 0; j < 4; ++j) bvv[j] = bias[bn + wn + j * 16 + l15];
  bool rope = (z < 2);
  int odd = l15 & 1;
#pragma unroll
  for (int i = 0; i < 4; ++i) {
#pragma unroll
    for (int j = 0; j < 4; ++j) {
#pragma unroll
      for (int r = 0; r < 4; ++r) {
        int m = bm + wm + i * 16 + lg * 4 + r;
        int n = bn + wn + j * 16 + l15;
        float v = acc[i][j][r] + bvv[j];
        if (rope) {
          int s = m & 2047;
          int dp = (j * 16 + l15) >> 1;  // (n&63)>>1
          float2 cs = tab[s * 32 + dp];
          float p = __shfl_xor(v, 1);
          float ps = p * cs.y;
          v = odd ? fmaf(v, cs.x, ps) : fmaf(v, cs.x, -ps);
        }
        int bb = m >> 11, ss = m & 2047, h = n >> 6, d = n & 63;
        dst[(((size_t)(bb * 16 + h)) * 2048 + ss) * 64 + d] = f2bf(v);
      }
    }
  }
}

// ---------------- causal flash attention, 32x32 MFMA, split-KV x4 ----------------
// grid 2048 blocks x 256 thr (4 waves). Block owns one 32-row q-tile of one bh.
// Wave w processes kv-tiles t%4==w (no barriers in loop). Fixed-max fast path
// (mrun=40 covers raw-score range; cold path fully correct), lane-partial lrun
// (one shfl at the end), in-place K prefetch of tile t+4. LDS tree-merge at end.
__global__ __launch_bounds__(256, 4) void k_attn(const u16* __restrict__ Q, const u16* __restrict__ K,
                                                 const u16* __restrict__ Vt, u16* __restrict__ ctx) {
  __shared__ float sM[2][64], sL[2][64];
  __shared__ float sO[2][32][64];  // [slot][reg][lane] - lane-contiguous, 2-way = free
  const float KL2E = 0.18033688011112042f;  // (1/8) * log2(e)
  int id = blockIdx.x;
  int bh = ((id >> 3) & 3) * 8 + (id & 7);  // XCD-cluster: bh%8 == id%8
  int qt = 63 - (id >> 5);                  // heavy q-tiles first
  int tid = threadIdx.x;
  int w = tid >> 6, lane = tid & 63;
  int q31 = lane & 31, h = lane >> 5;
  const u16* Qg = Q + (size_t)bh * 131072;
  const u16* Kg = K + (size_t)bh * 131072;
  const u16* Vg = Vt + (size_t)bh * 131072;
  int qrow = qt * 32 + q31;

  short8 qf[4];
#pragma unroll
  for (int m = 0; m < 4; ++m)
    qf[m] = *(const short8*)(Qg + (size_t)qrow * 64 + m * 16 + h * 8);

  f32x16 o0, o1;
#pragma unroll
  for (int r = 0; r < 16; ++r) { o0[r] = 0.f; o1[r] = 0.f; }
  float mrun = 40.0f, lrun = 0.f;  // lrun is lane-partial (this lane's 32 columns)
  int ntile = (qt >> 1) + 1;

  short8 kf0[4], kf1[4];
  if (w < ntile) {
    int kv = w << 6;
#pragma unroll
    for (int m = 0; m < 4; ++m) {
      kf0[m] = *(const short8*)(Kg + (size_t)(kv + q31) * 64 + m * 16 + h * 8);
      kf1[m] = *(const short8*)(Kg + (size_t)(kv + 32 + q31) * 64 + m * 16 + h * 8);
    }
  }

  for (int t = w; t < ntile; t += 4) {
    int kv = t << 6;
    f32x16 pA, pB;
#pragma unroll
    for (int r = 0; r < 16; ++r) { pA[r] = 0.f; pB[r] = 0.f; }
#pragma unroll
    for (int m = 0; m < 4; ++m) mfma32(pA, kf0[m], qf[m]);
#pragma unroll
    for (int m = 0; m < 4; ++m) mfma32(pB, kf1[m], qf[m]);

    if (t == ntile - 1) {  // diagonal tile: mask key > q
#pragma unroll
      for (int r = 0; r < 16; ++r) {
        int keyA = kv + (r & 3) + 8 * (r >> 2) + 4 * h;
        if (keyA > qrow) pA[r] = -1e9f;
        if (keyA + 32 > qrow) pB[r] = -1e9f;
      }
    }
    // guard: only a predicate (no cross-lane shfl on the fast path)
    {
      float u[8];
#pragma unroll
      for (int r = 0; r < 8; ++r)
        u[r] = fmaxf(fmaxf(pA[r], pA[r + 8]), fmaxf(pB[r], pB[r + 8]));
      u[0] = fmaxf(fmaxf(u[0], u[4]), fmaxf(u[1], u[5]));
      u[2] = fmaxf(fmaxf(u[2], u[6]), fmaxf(u[3], u[7]));
      float pm = fmaxf(u[0], u[2]);
      if (__builtin_expect(__any(pm > mrun), 0)) {  // cold path: true online-softmax step
        pm = fmaxf(pm, __shfl_xor(pm, 32));
        float mnew = fmaxf(mrun, pm);
        float alpha = exp2f((mrun - mnew) * KL2E);
        lrun *= alpha;
#pragma unroll
        for (int r = 0; r < 16; ++r) { o0[r] *= alpha; o1[r] *= alpha; }
        mrun = mnew;
      }
    }
    // exp + lane-partial sum (8 parallel accumulators)
    float sa0 = 0.f, sa1 = 0.f, sa2 = 0.f, sa3 = 0.f;
    float sb0 = 0.f, sb1 = 0.f, sb2 = 0.f, sb3 = 0.f;
#pragma unroll
    for (int r = 0; r < 16; r += 4) {
      pA[r + 0] = exp2f((pA[r + 0] - mrun) * KL2E); sa0 += pA[r + 0];
      pA[r + 1] = exp2f((pA[r + 1] - mrun) * KL2E); sa1 += pA[r + 1];
      pA[r + 2] = exp2f((pA[r + 2] - mrun) * KL2E); sa2 += pA[r + 2];
      pA[r + 3] = exp2f((pA[r + 3] - mrun) * KL2E); sa3 += pA[r + 3];
      pB[r + 0] = exp2f((pB[r + 0] - mrun) * KL2E); sb0 += pB[r + 0];
      pB[r + 1] = exp2f((pB[r + 1] - mrun) * KL2E); sb1 += pB[r + 1];
      pB[r + 2] = exp2f((pB[r + 2] - mrun) * KL2E); sb2 += pB[r + 2];
      pB[r + 3] = exp2f((pB[r + 3] - mrun) * KL2E); sb3 += pB[r + 3];
    }
    lrun += ((sa0 + sa1) + (sa2 + sa3)) + ((sb0 + sb1) + (sb2 + sb3));
    // V^T fragments
    short8 vf0[4], vf1[4];
#pragma unroll
    for (int m = 0; m < 4; ++m) {
      vf0[m] = *(const short8*)(Vg + (size_t)q31 * 2048 + kv + m * 16 + h * 8);
      vf1[m] = *(const short8*)(Vg + (size_t)(32 + q31) * 2048 + kv + m * 16 + h * 8);
    }
    // in-place K prefetch for tile t+4 (kf regs are dead after QK above)
    if (t + 4 < ntile) {
      int kvn = kv + 256;
#pragma unroll
      for (int m = 0; m < 4; ++m) {
        kf0[m] = *(const short8*)(Kg + (size_t)(kvn + q31) * 64 + m * 16 + h * 8);
        kf1[m] = *(const short8*)(Kg + (size_t)(kvn + 32 + q31) * 64 + m * 16 + h * 8);
      }
    }
    // P -> bf16 B-frags via cvt_pk + permlane32_swap; PV accumulate
#pragma unroll
    for (int m = 0; m < 4; ++m) {
      int mlow = 8 * (m & 1);
      u32 u0, u1, v0, v1;
      if (m < 2) {
        u0 = cvtpk(pA[mlow + 0], pA[mlow + 1]);
        u1 = cvtpk(pA[mlow + 2], pA[mlow + 3]);
        v0 = cvtpk(pA[mlow + 4], pA[mlow + 5]);
        v1 = cvtpk(pA[mlow + 6], pA[mlow + 7]);
      } else {
        u0 = cvtpk(pB[mlow + 0], pB[mlow + 1]);
        u1 = cvtpk(pB[mlow + 2], pB[mlow + 3]);
        v0 = cvtpk(pB[mlow + 4], pB[mlow + 5]);
        v1 = cvtpk(pB[mlow + 6], pB[mlow + 7]);
      }
      swap32(u0, v0);
      swap32(u1, v1);
      union { u32 wd[4]; short8 s; } pf;
      pf.wd[0] = u0; pf.wd[1] = u1; pf.wd[2] = v0; pf.wd[3] = v1;
      mfma32(o0, vf0[m], pf.s);
      mfma32(o1, vf1[m], pf.s);
    }
  }

  // ---- LDS tree merge of 4 per-wave partials (elementwise per lane) ----
#define STOREW(S)                                        \
  {                                                      \
    sM[S][lane] = mrun; sL[S][lane] = lrun;              \
    _Pragma("unroll") for (int r = 0; r < 16; ++r) {     \
      sO[S][r][lane] = o0[r];                            \
      sO[S][16 + r][lane] = o1[r];                       \
    }                                                    \
  }
#define MERGEW(S)                                                      \
  {                                                                    \
    float m2 = sM[S][lane], l2 = sL[S][lane];                          \
    float mn = fmaxf(mrun, m2);                                        \
    float a = exp2f((mrun - mn) * KL2E);                               \
    float b = exp2f((m2 - mn) * KL2E);                                 \
    lrun = lrun * a + l2 * b;                                          \
    _Pragma("unroll") for (int r = 0; r < 16; ++r) {                   \
      o0[r] = o0[r] * a + sO[S][r][lane] * b;                          \
      o1[r] = o1[r] * a + sO[S][16 + r][lane] * b;                     \
    }                                                                  \
    mrun = mn;                                                         \
  }

  if (w == 1) STOREW(0);
  if (w == 3) STOREW(1);
  __syncthreads();
  if (w == 0) MERGEW(0);
  if (w == 2) MERGEW(1);
  __syncthreads();
  if (w == 2) STOREW(0);
  __syncthreads();
  if (w == 0) {
    MERGEW(0);
    lrun += __shfl_xor(lrun, 32);  // combine the two column-halves of each q-row
    float rl = 1.f / lrun;
    int bb = bh >> 4, hh = bh & 15;
    u16* base = ctx + ((size_t)(bb * 2048 + qrow)) * 1024 + hh * 64;
#pragma unroll
    for (int r = 0; r < 4; ++r) {
      uint2 pk;
      pk.x = cvtpk(o0[4 * r + 0] * rl, o0[4 * r + 1] * rl);
      pk.y = cvtpk(o0[4 * r + 2] * rl, o0[4 * r + 3] * rl);
      *(uint2*)(base + 8 * r + 4 * h) = pk;
      uint2 pk2;
      pk2.x = cvtpk(o1[4 * r + 0] * rl, o1[4 * r + 1] * rl);
      pk2.y = cvtpk(o1[4 * r + 2] * rl, o1[4 * r + 3] * rl);
      *(uint2*)(base + 32 + 8 * r + 4 * h) = pk2;
    }
  }
#undef STOREW
#undef MERGEW
}

extern "C" void kernel_launch(void* const* d_in, const int* in_sizes, int n_in,
                              void* d_out, int out_size, void* d_ws, size_t ws_size,
                              hipStream_t stream) {
  (void)in_sizes; (void)n_in; (void)out_size; (void)ws_size;
  const float* xq = (const float*)d_in[0];
  const float* xk = (const float*)d_in[1];
  const float* xv = (const float*)d_in[2];
  const float* Wq = (const float*)d_in[4];
  const float* bq = (const float*)d_in[5];
  const float* Wk = (const float*)d_in[6];
  const float* bk = (const float*)d_in[7];
  const float* Wv = (const float*)d_in[8];
  const float* bv = (const float*)d_in[9];
  const float* Wo = (const float*)d_in[10];
  const float* bo = (const float*)d_in[11];

  char* ws = (char*)d_ws;
  u16* XQ  = (u16*)(ws);                       // 8MB, dead after QKV gemm
  u16* XK  = (u16*)(ws + ((size_t)8 << 20));   // 8MB, dead after QKV gemm
  u16* XV  = (u16*)(ws + ((size_t)16 << 20));  // 8MB
  u16* WTQ = (u16*)(ws + ((size_t)24 << 20));  // 2MB each
  u16* WTK = (u16*)(ws + ((size_t)26 << 20));
  u16* WTV = (u16*)(ws + ((size_t)28 << 20));
  u16* WTO = (u16*)(ws + ((size_t)30 << 20));
  u16* Qb  = (u16*)(ws + ((size_t)32 << 20));  // 8MB (32,2048,64) bf16
  u16* Kb  = (u16*)(ws + ((size_t)40 << 20));
  u16* Vb  = (u16*)(ws + ((size_t)48 << 20));
  u16* VT  = (u16*)(ws + ((size_t)8 << 20));   // aliases XK (dead) - (32,64,2048) bf16
  u16* CTX = (u16*)(ws);                       // aliases XQ (dead)
  float2* TAB = (float2*)d_out;                // 512KB rope table; d_out is free until final GEMM

  k_prep<<<7424, 256, 0, stream>>>(xq, xk, xv, XQ, XK, XV, Wq, Wk, Wv, Wo, WTQ, WTK, WTV, WTO, TAB);
  dim3 gq(32, 8, 3);
  k_gemm_qkv<<<gq, 256, 0, stream>>>(XQ, XK, XV, WTQ, WTK, WTV, bq, bk, bv, TAB, Qb, Kb, Vb);
  dim3 vtg(32, 32);
  k_vtrans<<<vtg, 256, 0, stream>>>(Vb, VT);
  k_attn<<<2048, 256, 0, stream>>>(Qb, Kb, VT, CTX);
  dim3 gg(32, 8);
  k_gemm<1><<<gg, 256, 0, stream>>>(CTX, WTO, bo, d_out);
}

// Round 9
// 148.543 us; speedup vs baseline: 1.4916x; 1.4916x over previous
//
#include <hip/hip_runtime.h>

typedef unsigned short u16;
typedef unsigned int u32;
typedef __attribute__((ext_vector_type(8))) short short8;
typedef __attribute__((ext_vector_type(4))) float f32x4;
typedef __attribute__((ext_vector_type(16))) float f32x16;

#define DEV static __device__ __forceinline__

DEV u16 f2bf(float x) {
  union { float f; u32 u; } v; v.f = x;
  u32 r = v.u + 0x7fffu + ((v.u >> 16) & 1u);
  return (u16)(r >> 16);
}
DEV float bf2f(u16 x) {
  union { u32 u; float f; } v; v.u = ((u32)x) << 16;
  return v.f;
}
DEV u32 cvtpk(float lo, float hi) {  // D.lo=bf16(lo), D.hi=bf16(hi), RNE
  u32 r;
  asm("v_cvt_pk_bf16_f32 %0, %1, %2" : "=v"(r) : "v"(lo), "v"(hi));
  return r;
}
DEV void swap32(u32& a, u32& b) {  // a' = [a.lo32 | b.lo32], b' = [a.hi32 | b.hi32]
  asm("v_permlane32_swap_b32 %0, %1" : "+v"(a), "+v"(b));
}

DEV void gload_lds16(const void* g, void* l) {
  __builtin_amdgcn_global_load_lds(
      (__attribute__((address_space(1))) u32*)((void*)g),
      (__attribute__((address_space(3))) u32*)l, 16, 0, 0);
}

DEV void mfma_bf16(f32x4& d, short8 a, short8 b) {
  asm("v_mfma_f32_16x16x32_bf16 %0, %1, %2, %0" : "+v"(d) : "v"(a), "v"(b));
}
DEV void mfma32(f32x16& d, short8 a, short8 b) {
  asm("v_mfma_f32_32x32x16_bf16 %0, %1, %2, %0" : "+v"(d) : "v"(a), "v"(b));
}

// ---------------- fused prep: x->bf16 (blocks 0..6143), W->Wt bf16 (6144..7167),
// ---------------- rope sincos table (7168..7423) ----------------
__global__ __launch_bounds__(256) void k_prep(const float* __restrict__ x0, const float* __restrict__ x1,
                                              const float* __restrict__ x2, u16* __restrict__ o0,
                                              u16* __restrict__ o1, u16* __restrict__ o2,
                                              const float* __restrict__ W0, const float* __restrict__ W1,
                                              const float* __restrict__ W2, const float* __restrict__ W3,
                                              u16* __restrict__ T0, u16* __restrict__ T1,
                                              u16* __restrict__ T2, u16* __restrict__ T3,
                                              float2* __restrict__ tab) {
  int bid = blockIdx.x;
  int t = threadIdx.x;
  if (bid < 6144) {  // fp32 -> bf16 cast, 8 elems/thread
    int z = bid >> 11;
    const float* in = (z == 0) ? x0 : (z == 1) ? x1 : x2;
    u16* out = (z == 0) ? o0 : (z == 1) ? o1 : o2;
    int i = (bid & 2047) * 256 + t;
    const float4* p = (const float4*)in;
    float4 a = p[i * 2], b = p[i * 2 + 1];
    uint4 o;
    o.x = cvtpk(a.x, a.y); o.y = cvtpk(a.z, a.w);
    o.z = cvtpk(b.x, b.y); o.w = cvtpk(b.z, b.w);
    ((uint4*)out)[i] = o;
  } else if (bid < 7168) {  // W[k][n] -> Wt[n][k] bf16, 64x64 tile
    int q = bid - 6144;
    int z = q >> 8;
    const float* W = (z == 0) ? W0 : (z == 1) ? W1 : (z == 2) ? W2 : W3;
    u16* Wt = (z == 0) ? T0 : (z == 1) ? T1 : (z == 2) ? T2 : T3;
    __shared__ u16 tile[64][65];
    int k0 = ((q >> 4) & 15) * 64, n0 = (q & 15) * 64;
    int rr = t >> 4, cc = (t & 15) * 4;
#pragma unroll
    for (int i = 0; i < 4; ++i) {
      int r = rr + i * 16;
      float4 v = *(const float4*)&W[(size_t)(k0 + r) * 1024 + n0 + cc];
      tile[r][cc + 0] = f2bf(v.x); tile[r][cc + 1] = f2bf(v.y);
      tile[r][cc + 2] = f2bf(v.z); tile[r][cc + 3] = f2bf(v.w);
    }
    __syncthreads();
#pragma unroll
    for (int i = 0; i < 4; ++i) {
      int n = rr + i * 16;
      u16 a0 = tile[cc + 0][n], a1 = tile[cc + 1][n], a2 = tile[cc + 2][n], a3 = tile[cc + 3][n];
      uint2 pk;
      pk.x = (u32)a0 | ((u32)a1 << 16);
      pk.y = (u32)a2 | ((u32)a3 << 16);
      *(uint2*)&Wt[(size_t)(n0 + n) * 1024 + k0 + cc] = pk;
    }
  } else {  // rope table: tab[s*32+dp] = (cos, sin) of s * 10000^(-dp/32)
    int idx = (bid - 7168) * 256 + t;
    int s = idx >> 5, dp = idx & 31;
    float theta = exp2f((float)dp * (-2.0f / 64.0f) * 13.287712379549449f);
    float ang = (float)s * theta;
    float sn, cs;
    sincosf(ang, &sn, &cs);
    tab[idx] = make_float2(cs, sn);
  }
}

// ---------------- GEMM core, BK=64, XOR-swizzled LDS (2-way conflict = free) ----------------
#define GEMM_BODY(A_, Bt_)                                                                       \
  __shared__ __align__(16) char sA[16384];                                                       \
  __shared__ __align__(16) char sB[16384];                                                       \
  int tid = threadIdx.x, lane = tid & 63, w = tid >> 6;                                          \
  int l15 = lane & 15, lg = lane >> 4;                                                           \
  int bm = blockIdx.x * 128, bn = blockIdx.y * 128;                                              \
  int wm = (w >> 1) * 64, wn = (w & 1) * 64;                                                     \
  f32x4 acc[4][4];                                                                               \
  _Pragma("unroll") for (int i = 0; i < 4; ++i)                                                  \
      _Pragma("unroll") for (int j = 0; j < 4; ++j) acc[i][j] = (f32x4){0.f, 0.f, 0.f, 0.f};     \
  for (int kt = 0; kt < 16; ++kt) {                                                              \
    _Pragma("unroll") for (int p = 0; p < 4; ++p) {                                              \
      int idx = p * 256 + tid;                                                                   \
      int row = idx >> 3;                                                                        \
      int c8 = (idx & 7) ^ (row & 7);                                                            \
      gload_lds16(A_ + (size_t)(bm + row) * 1024 + kt * 64 + c8 * 8, sA + p * 4096 + w * 1024);  \
      gload_lds16(Bt_ + (size_t)(bn + row) * 1024 + kt * 64 + c8 * 8, sB + p * 4096 + w * 1024); \
    }                                                                                            \
    __syncthreads();                                                                             \
    short8 af[4][2], bf[4][2];                                                                   \
    _Pragma("unroll") for (int i = 0; i < 4; ++i) _Pragma("unroll") for (int s = 0; s < 2; ++s) { \
      int cs = ((s * 4 + lg) ^ (l15 & 7)) * 16;                                                  \
      af[i][s] = *(const short8*)(sA + (wm + i * 16 + l15) * 128 + cs);                          \
      bf[i][s] = *(const short8*)(sB + (wn + i * 16 + l15) * 128 + cs);                          \
    }                                                                                            \
    _Pragma("unroll") for (int s = 0; s < 2; ++s)                                                \
        _Pragma("unroll") for (int i = 0; i < 4; ++i)                                            \
            _Pragma("unroll") for (int j = 0; j < 4; ++j) mfma_bf16(acc[i][j], af[i][s], bf[j][s]); \
    __syncthreads();                                                                             \
  }

// MODE 1: write fp32 row-major (output projection).
template <int MODE>
__global__ __launch_bounds__(256) void k_gemm(const u16* __restrict__ A, const u16* __restrict__ Bt,
                                              const float* __restrict__ bias, void* __restrict__ dst) {
  GEMM_BODY(A, Bt)
  float bv[4];
#pragma unroll
  for (int j = 0; j < 4; ++j) bv[j] = bias[bn + wn + j * 16 + l15];
#pragma unroll
  for (int i = 0; i < 4; ++i) {
#pragma unroll
    for (int j = 0; j < 4; ++j) {
#pragma unroll
      for (int r = 0; r < 4; ++r) {
        int m = bm + wm + i * 16 + lg * 4 + r;
        int n = bn + wn + j * 16 + l15;
        float v = acc[i][j][r] + bv[j];
        if (MODE == 0) {
          int bb = m >> 11, s = m & 2047, h = n >> 6, d = n & 63;
          ((u16*)dst)[(((size_t)(bb * 16 + h)) * 2048 + s) * 64 + d] = f2bf(v);
        } else {
          ((float*)dst)[(size_t)m * 1024 + n] = v;
        }
      }
    }
  }
}

// QKV fused over blockIdx.z; RoPE fused into epilogue for z<2 (Q,K).
// z==2 (V) writes DIRECTLY TRANSPOSED (b,h,d,s) - removes the k_vtrans pass.
// Per (i,j) the 4 r-values are contiguous in s -> one 8B uint2 store.
__global__ __launch_bounds__(256) void k_gemm_qkv(const u16* __restrict__ Aq, const u16* __restrict__ Ak,
                                                  const u16* __restrict__ Av, const u16* __restrict__ Wq,
                                                  const u16* __restrict__ Wk, const u16* __restrict__ Wv,
                                                  const float* __restrict__ bq, const float* __restrict__ bk,
                                                  const float* __restrict__ bv,
                                                  const float2* __restrict__ tab, u16* __restrict__ Qo,
                                                  u16* __restrict__ Ko, u16* __restrict__ VTo) {
  int z = blockIdx.z;
  const u16* A = (z == 0) ? Aq : (z == 1) ? Ak : Av;
  const u16* Bt = (z == 0) ? Wq : (z == 1) ? Wk : Wv;
  const float* bias = (z == 0) ? bq : (z == 1) ? bk : bv;
  GEMM_BODY(A, Bt)
  float bvv[4];
#pragma unroll
  for (int j = 0; j < 4; ++j) bvv[j] = bias[bn + wn + j * 16 + l15];
  if (z == 2) {  // V: transposed write VT[bh][d][s]
#pragma unroll
    for (int i = 0; i < 4; ++i) {
#pragma unroll
      for (int j = 0; j < 4; ++j) {
        int m = bm + wm + i * 16 + lg * 4;  // r=0 base; r spans 4 contiguous s
        int n = bn + wn + j * 16 + l15;
        int bb = m >> 11, s = m & 2047, h = n >> 6, d = n & 63;
        uint2 pk;
        pk.x = cvtpk(acc[i][j][0] + bvv[j], acc[i][j][1] + bvv[j]);
        pk.y = cvtpk(acc[i][j][2] + bvv[j], acc[i][j][3] + bvv[j]);
        *(uint2*)(VTo + (((size_t)(bb * 16 + h)) * 64 + d) * 2048 + s) = pk;
      }
    }
    return;
  }
  u16* dst = (z == 0) ? Qo : Ko;
  int odd = l15 & 1;
#pragma unroll
  for (int i = 0; i < 4; ++i) {
#pragma unroll
    for (int j = 0; j < 4; ++j) {
#pragma unroll
      for (int r = 0; r < 4; ++r) {
        int m = bm + wm + i * 16 + lg * 4 + r;
        int n = bn + wn + j * 16 + l15;
        float v = acc[i][j][r] + bvv[j];
        {
          int s = m & 2047;
          int dp = (j * 16 + l15) >> 1;  // (n&63)>>1
          float2 cs = tab[s * 32 + dp];
          float p = __shfl_xor(v, 1);
          float ps = p * cs.y;
          v = odd ? fmaf(v, cs.x, ps) : fmaf(v, cs.x, -ps);
        }
        int bb = m >> 11, ss = m & 2047, h = n >> 6, d = n & 63;
        dst[(((size_t)(bb * 16 + h)) * 2048 + ss) * 64 + d] = f2bf(v);
      }
    }
  }
}

// ---------------- causal flash attention, 32x32 MFMA, split-KV x4 (round-7 proven, 81us) ----------------
__global__ __launch_bounds__(256, 4) void k_attn(const u16* __restrict__ Q, const u16* __restrict__ K,
                                                 const u16* __restrict__ Vt, u16* __restrict__ ctx) {
  __shared__ float sM[2][64], sL[2][64];
  __shared__ float sO[2][32][64];  // [slot][reg][lane] - lane-contiguous, 2-way = free
  const float KL2E = 0.18033688011112042f;  // (1/8) * log2(e)
  int id = blockIdx.x;
  int bh = ((id >> 3) & 3) * 8 + (id & 7);  // XCD-cluster: bh%8 == id%8
  int qt = 63 - (id >> 5);                  // heavy q-tiles first
  int tid = threadIdx.x;
  int w = tid >> 6, lane = tid & 63;
  int q31 = lane & 31, h = lane >> 5;
  const u16* Qg = Q + (size_t)bh * 131072;
  const u16* Kg = K + (size_t)bh * 131072;
  const u16* Vg = Vt + (size_t)bh * 131072;
  int qrow = qt * 32 + q31;

  short8 qf[4];
#pragma unroll
  for (int m = 0; m < 4; ++m)
    qf[m] = *(const short8*)(Qg + (size_t)qrow * 64 + m * 16 + h * 8);

  f32x16 o0, o1;
#pragma unroll
  for (int r = 0; r < 16; ++r) { o0[r] = 0.f; o1[r] = 0.f; }
  float mrun = -3e38f, lrun = 0.f;
  int ntile = (qt >> 1) + 1;

  for (int t = w; t < ntile; t += 4) {
    int kv = t << 6;
    // K fragments: A[row=key(lane&31)][k = d-slice m*16+h*8..+7]
    short8 kf0[4], kf1[4];
#pragma unroll
    for (int m = 0; m < 4; ++m) {
      kf0[m] = *(const short8*)(Kg + (size_t)(kv + q31) * 64 + m * 16 + h * 8);
      kf1[m] = *(const short8*)(Kg + (size_t)(kv + 32 + q31) * 64 + m * 16 + h * 8);
    }
    f32x16 pA, pB;
#pragma unroll
    for (int r = 0; r < 16; ++r) { pA[r] = 0.f; pB[r] = 0.f; }
#pragma unroll
    for (int m = 0; m < 4; ++m) mfma32(pA, kf0[m], qf[m]);
#pragma unroll
    for (int m = 0; m < 4; ++m) mfma32(pB, kf1[m], qf[m]);

    if (t == ntile - 1) {  // diagonal tile: mask key > q
#pragma unroll
      for (int r = 0; r < 16; ++r) {
        int keyA = kv + (r & 3) + 8 * (r >> 2) + 4 * h;
        if (keyA > qrow) pA[r] = -1e9f;
        if (keyA + 32 > qrow) pB[r] = -1e9f;
      }
    }
    // online softmax: lane owns q-row q31 (16 keys here, other 16 in lane^32)
    float pm = pA[0];
#pragma unroll
    for (int r = 1; r < 16; ++r) pm = fmaxf(pm, pA[r]);
#pragma unroll
    for (int r = 0; r < 16; ++r) pm = fmaxf(pm, pB[r]);
    pm = fmaxf(pm, __shfl_xor(pm, 32));
    float mnew = fmaxf(mrun, pm);
    int upd = pm > mrun;
    float alpha = exp2f((mrun - mnew) * KL2E);
    mrun = mnew;
    float ps = 0.f;
#pragma unroll
    for (int r = 0; r < 16; ++r) {
      pA[r] = exp2f((pA[r] - mnew) * KL2E);
      ps += pA[r];
    }
#pragma unroll
    for (int r = 0; r < 16; ++r) {
      pB[r] = exp2f((pB[r] - mnew) * KL2E);
      ps += pB[r];
    }
    ps += __shfl_xor(ps, 32);
    lrun = lrun * alpha + ps;
    if (__any(upd)) {
#pragma unroll
      for (int r = 0; r < 16; ++r) { o0[r] *= alpha; o1[r] *= alpha; }
    }
    // V^T fragments: A[row=d(lane&31)][k = key m*16+h*8..+7]
    short8 vf0[4], vf1[4];
#pragma unroll
    for (int m = 0; m < 4; ++m) {
      vf0[m] = *(const short8*)(Vg + (size_t)q31 * 2048 + kv + m * 16 + h * 8);
      vf1[m] = *(const short8*)(Vg + (size_t)(32 + q31) * 2048 + kv + m * 16 + h * 8);
    }
    // P -> bf16 B-frags via cvt_pk + permlane32_swap; PV accumulate
#pragma unroll
    for (int m = 0; m < 4; ++m) {
      int mlow = 8 * (m & 1);
      u32 u0, u1, v0, v1;
      if (m < 2) {
        u0 = cvtpk(pA[mlow + 0], pA[mlow + 1]);
        u1 = cvtpk(pA[mlow + 2], pA[mlow + 3]);
        v0 = cvtpk(pA[mlow + 4], pA[mlow + 5]);
        v1 = cvtpk(pA[mlow + 6], pA[mlow + 7]);
      } else {
        u0 = cvtpk(pB[mlow + 0], pB[mlow + 1]);
        u1 = cvtpk(pB[mlow + 2], pB[mlow + 3]);
        v0 = cvtpk(pB[mlow + 4], pB[mlow + 5]);
        v1 = cvtpk(pB[mlow + 6], pB[mlow + 7]);
      }
      swap32(u0, v0);
      swap32(u1, v1);
      union { u32 wd[4]; short8 s; } pf;
      pf.wd[0] = u0; pf.wd[1] = u1; pf.wd[2] = v0; pf.wd[3] = v1;
      mfma32(o0, vf0[m], pf.s);
      mfma32(o1, vf1[m], pf.s);
    }
  }

  // ---- LDS tree merge of 4 per-wave partials (elementwise per lane) ----
#define STOREW(S)                                        \
  {                                                      \
    sM[S][lane] = mrun; sL[S][lane] = lrun;              \
    _Pragma("unroll") for (int r = 0; r < 16; ++r) {     \
      sO[S][r][lane] = o0[r];                            \
      sO[S][16 + r][lane] = o1[r];                       \
    }                                                    \
  }
#define MERGEW(S)                                                      \
  {                                                                    \
    float m2 = sM[S][lane], l2 = sL[S][lane];                          \
    float mn = fmaxf(mrun, m2);                                        \
    float a = exp2f((mrun - mn) * KL2E);                               \
    float b = exp2f((m2 - mn) * KL2E);                                 \
    lrun = lrun * a + l2 * b;                                          \
    _Pragma("unroll") for (int r = 0; r < 16; ++r) {                   \
      o0[r] = o0[r] * a + sO[S][r][lane] * b;                          \
      o1[r] = o1[r] * a + sO[S][16 + r][lane] * b;                     \
    }                                                                  \
    mrun = mn;                                                         \
  }

  if (w == 1) STOREW(0);
  if (w == 3) STOREW(1);
  __syncthreads();
  if (w == 0) MERGEW(0);
  if (w == 2) MERGEW(1);
  __syncthreads();
  if (w == 2) STOREW(0);
  __syncthreads();
  if (w == 0) {
    MERGEW(0);
    float rl = 1.f / lrun;
    int bb = bh >> 4, hh = bh & 15;
    u16* base = ctx + ((size_t)(bb * 2048 + qrow)) * 1024 + hh * 64;
#pragma unroll
    for (int r = 0; r < 4; ++r) {
      uint2 pk;
      pk.x = cvtpk(o0[4 * r + 0] * rl, o0[4 * r + 1] * rl);
      pk.y = cvtpk(o0[4 * r + 2] * rl, o0[4 * r + 3] * rl);
      *(uint2*)(base + 8 * r + 4 * h) = pk;
      uint2 pk2;
      pk2.x = cvtpk(o1[4 * r + 0] * rl, o1[4 * r + 1] * rl);
      pk2.y = cvtpk(o1[4 * r + 2] * rl, o1[4 * r + 3] * rl);
      *(uint2*)(base + 32 + 8 * r + 4 * h) = pk2;
    }
  }
#undef STOREW
#undef MERGEW
}

extern "C" void kernel_launch(void* const* d_in, const int* in_sizes, int n_in,
                              void* d_out, int out_size, void* d_ws, size_t ws_size,
                              hipStream_t stream) {
  (void)in_sizes; (void)n_in; (void)out_size; (void)ws_size;
  const float* xq = (const float*)d_in[0];
  const float* xk = (const float*)d_in[1];
  const float* xv = (const float*)d_in[2];
  const float* Wq = (const float*)d_in[4];
  const float* bq = (const float*)d_in[5];
  const float* Wk = (const float*)d_in[6];
  const float* bk = (const float*)d_in[7];
  const float* Wv = (const float*)d_in[8];
  const float* bv = (const float*)d_in[9];
  const float* Wo = (const float*)d_in[10];
  const float* bo = (const float*)d_in[11];

  char* ws = (char*)d_ws;
  u16* XQ  = (u16*)(ws);                       // 8MB, dead after QKV gemm
  u16* XK  = (u16*)(ws + ((size_t)8 << 20));   // 8MB, dead after QKV gemm
  u16* XV  = (u16*)(ws + ((size_t)16 << 20));  // 8MB
  u16* WTQ = (u16*)(ws + ((size_t)24 << 20));  // 2MB each
  u16* WTK = (u16*)(ws + ((size_t)26 << 20));
  u16* WTV = (u16*)(ws + ((size_t)28 << 20));
  u16* WTO = (u16*)(ws + ((size_t)30 << 20));
  u16* Qb  = (u16*)(ws + ((size_t)32 << 20));  // 8MB (32,2048,64) bf16
  u16* Kb  = (u16*)(ws + ((size_t)40 << 20));
  u16* VT  = (u16*)(ws + ((size_t)48 << 20));  // (32,64,2048) bf16, written by qkv z==2
  u16* CTX = (u16*)(ws);                       // aliases XQ (dead after qkv)
  float2* TAB = (float2*)d_out;                // 512KB rope table; d_out is free until final GEMM

  k_prep<<<7424, 256, 0, stream>>>(xq, xk, xv, XQ, XK, XV, Wq, Wk, Wv, Wo, WTQ, WTK, WTV, WTO, TAB);
  dim3 gq(32, 8, 3);
  k_gemm_qkv<<<gq, 256, 0, stream>>>(XQ, XK, XV, WTQ, WTK, WTV, bq, bk, bv, TAB, Qb, Kb, VT);
  k_attn<<<2048, 256, 0, stream>>>(Qb, Kb, VT, CTX);
  dim3 gg(32, 8);
  k_gemm<1><<<gg, 256, 0, stream>>>(CTX, WTO, bo, d_out);
}